// Round 7
// baseline (172.712 us; speedup 1.0000x reference)
//
#include <hip/hip_runtime.h>
#include <math.h>

#define NROWS 8192
#define HALF  4096
#define EMB   2048
#define DIM   256
#define INV_T 10.0f

typedef __bf16 bf16x8v __attribute__((ext_vector_type(8)));
typedef __bf16 bf16x4v __attribute__((ext_vector_type(4)));
typedef float  f32x4   __attribute__((ext_vector_type(4)));

__device__ __forceinline__ void gld_lds16(const void* g, void* l) {
    __builtin_amdgcn_global_load_lds((const __attribute__((address_space(1))) void*)g,
                                     (__attribute__((address_space(3))) void*)l,
                                     16, 0, 0);
}

// ---------- K0: W [2048][256] f32 -> Wt [256][2048] bf16, coalesced tile transpose ----------
__global__ __launch_bounds__(256) void wt_kernel(const float* __restrict__ W,
                                                 __bf16* __restrict__ Wt) {
    __shared__ __bf16 t[64][72];
    const int n0 = blockIdx.x * 64;
    const int k0 = blockIdx.y * 64;
    const int tid = threadIdx.x;
    const int c = tid & 63;
    const int rr = tid >> 6;
#pragma unroll
    for (int it = 0; it < 16; it++) {
        int k = it * 4 + rr;
        t[k][c] = (__bf16)W[(size_t)(k0 + k) * DIM + n0 + c];
    }
    __syncthreads();
#pragma unroll
    for (int it = 0; it < 16; it++) {
        int n = it * 4 + rr;
        Wt[(size_t)(n0 + n) * EMB + k0 + c] = t[c][n];
    }
}

// ---------- K1a: head GEMM. v7: T3-minimal 2-PHASE DOUBLE BUFFER. ----------
// v6 (and every 40-46us variant) used stage -> barrier -> compute -> barrier:
// tile t's loads are drained (vmcnt(0) in __syncthreads) BEFORE any compute,
// exposing full L2/HBM latency on all 32 iterations. v7: issue STAGE(t+1),
// compute(t), ONE barrier -- the drain waits on loads issued ~350cy earlier,
// covered by this iteration's MFMA + ds_reads (guide T3 recipe, m248v2).
// Grid swapped to col-fastest: the 4 blocks sharing an A-stripe run
// concurrently -> A fetched from HBM once, shared via L2/L3.
#define GBM 32
#define GBN 64
#define GBK 64

__global__ __launch_bounds__(256, 4) void head_gemm(
    const float* __restrict__ A,      // [8192][2048] f32
    const __bf16* __restrict__ Wt,    // [256][2048] bf16
    const float* __restrict__ bias,   // [256] f32
    float* __restrict__ out8)         // [8192][256] f32 head+bias
{
    __shared__ __bf16 a_sh[2][GBM][GBK];   // 8 KB
    __shared__ __bf16 b_sh[2][GBN][GBK];   // 16 KB

    const int tid  = threadIdx.x;
    const int wave = tid >> 6, lane = tid & 63;
    const int quad = lane >> 4, l15 = lane & 15;
    const int colBase = blockIdx.x * GBN;   // x = col block (4) -> fastest
    const int rowBase = blockIdx.y * GBM;   // y = row block (256)
    const int wr = wave >> 1;   // 0..1: 16-row half
    const int wc = wave & 1;    // 0..1: 32-col half

    // A staging: thread -> row tid>>3 (0..31), granule tid&7 (8 f32 -> 8 bf16)
    const int ar = tid >> 3, ag = tid & 7;
    const float* aPtr = A + (size_t)(rowBase + ar) * EMB + ag * 8;
    const int aDstOff = ar * GBK + (ag ^ (ar & 7)) * 8;   // bf16 units in one buf

    // B staging: wave stages chunks {wave*2, wave*2+1}; chunk = 8 cols = 1KB.
    // source granule pre-swizzled g ^ (col&7); LDS dest linear (rule #21).
    size_t bSrcOff[2];
    int    bDstOff[2];
#pragma unroll
    for (int j = 0; j < 2; j++) {
        const int chunk = wave * 2 + j;
        const int c = chunk * 8 + (lane >> 3);
        const int g = lane & 7;
        bSrcOff[j] = (size_t)(colBase + c) * EMB + (g ^ (c & 7)) * 8;
        bDstOff[j] = chunk * 512;
    }

    f32x4 acc[2];
    const f32x4 zero = {0.f, 0.f, 0.f, 0.f};
    acc[0] = zero; acc[1] = zero;

    float bv[2];
#pragma unroll
    for (int n = 0; n < 2; n++) bv[n] = bias[colBase + wc * 32 + n * 16 + l15];

    // ---- prologue: stage tile 0 into buffer 0 ----
    {
        gld_lds16(Wt + bSrcOff[0], &b_sh[0][0][0] + bDstOff[0]);
        gld_lds16(Wt + bSrcOff[1], &b_sh[0][0][0] + bDstOff[1]);
        f32x4 lo = *(const f32x4*)(aPtr);
        f32x4 hi = *(const f32x4*)(aPtr + 4);
        bf16x8v av;
#pragma unroll
        for (int i = 0; i < 4; i++) { av[i] = (__bf16)lo[i]; av[4 + i] = (__bf16)hi[i]; }
        *(bf16x8v*)(&a_sh[0][0][0] + aDstOff) = av;
    }
    __syncthreads();

    // ---- main loop: ONE barrier per iter; stage(t+1) overlaps compute(t) ----
#pragma unroll 2
    for (int kk = 0; kk < EMB; kk += GBK) {
        const int p = (kk >> 6) & 1;
        const bool more = (kk + GBK < EMB);
        f32x4 lo, hi;
        if (more) {
            gld_lds16(Wt + bSrcOff[0] + kk + GBK, &b_sh[p ^ 1][0][0] + bDstOff[0]);
            gld_lds16(Wt + bSrcOff[1] + kk + GBK, &b_sh[p ^ 1][0][0] + bDstOff[1]);
            lo = *(const f32x4*)(aPtr + kk + GBK);
            hi = *(const f32x4*)(aPtr + kk + GBK + 4);
        }
        // compute buffer p
#pragma unroll
        for (int ks = 0; ks < 2; ks++) {
            const int arow = wr * 16 + l15;
            bf16x8v af = *(const bf16x8v*)&a_sh[p][arow][(((ks * 4 + quad) ^ (arow & 7)) * 8)];
#pragma unroll
            for (int n = 0; n < 2; n++) {
                const int col = wc * 32 + n * 16 + l15;
                bf16x8v bf = *(const bf16x8v*)&b_sh[p][col][(((ks * 4 + quad) ^ (col & 7)) * 8)];
                acc[n] = __builtin_amdgcn_mfma_f32_16x16x32_bf16(af, bf, acc[n], 0, 0, 0);
            }
        }
        if (more) {
            bf16x8v av;
#pragma unroll
            for (int i = 0; i < 4; i++) { av[i] = (__bf16)lo[i]; av[4 + i] = (__bf16)hi[i]; }
            *(bf16x8v*)(&a_sh[p ^ 1][0][0] + aDstOff) = av;
        }
        __syncthreads();   // drains this iter's ds_write + next-tile gld (issued early)
    }

    // epilogue: + bias, f32 store
#pragma unroll
    for (int n = 0; n < 2; n++)
#pragma unroll
        for (int r = 0; r < 4; r++) {
            const int grow = rowBase + wr * 16 + quad * 4 + r;
            const int gcol = colBase + wc * 32 + n * 16 + l15;
            out8[(size_t)grow * DIM + gcol] = acc[n][r] + bv[n];
        }
}

// ---------- K1b: L2-normalize rows of out8, emit bf16 X ----------
__global__ __launch_bounds__(256) void norm2_kernel(
    const float* __restrict__ out8,
    __bf16* __restrict__ outb)
{
    const int tid  = threadIdx.x;
    const int wave = tid >> 6, lane = tid & 63;
    const int row  = blockIdx.x * 4 + wave;

    float4 v = *(const float4*)(out8 + (size_t)row * DIM + lane * 4);
    float ss = v.x * v.x + v.y * v.y + v.z * v.z + v.w * v.w;
#pragma unroll
    for (int off = 1; off < 64; off <<= 1) ss += __shfl_xor(ss, off, 64);
    float inv = 1.f / fmaxf(sqrtf(ss), 1e-12f);

    bf16x4v o;
    o[0] = (__bf16)(v.x * inv); o[1] = (__bf16)(v.y * inv);
    o[2] = (__bf16)(v.z * inv); o[3] = (__bf16)(v.w * inv);
    *(bf16x4v*)(outb + (size_t)row * DIM + lane * 4) = o;
}

// ---------- K2: sim = X@X^T. v7: 2-phase double-buffered staging (64 KB LDS,
//              one barrier per K-chunk), XOR-swizzle, unique-writer epilogue ----------
#define TILE 128
#define NTILE (NROWS / TILE)              // 64
#define NBLK  (NTILE * (NTILE + 1) / 2)   // 2080

__global__ __launch_bounds__(256, 2) void sim_kernel(
    const __bf16* __restrict__ X,
    float* __restrict__ total,
    float* __restrict__ posv)
{
    // 64 KB: two 32 KB buffers, each [A|B] with [2][128][32] bf16 halves.
    // Reduce scratch reuses buffer 0 after the K-loop.
    __shared__ __align__(16) char smem[65536];
    float* rs = (float*)smem;              // [128][2][16] = 16 KB
    float* cs = (float*)(smem + 16384);    // [128][2][4]  = 4 KB

    const int t = blockIdx.x;
    int bx = (int)((129.0 - sqrt(16641.0 - 8.0 * (double)t)) * 0.5);
    while (64 * (bx + 1) - ((bx + 1) * bx) / 2 <= t) bx++;
    while (64 * bx - (bx * (bx - 1)) / 2 > t) bx--;
    const int by = bx + (t - (64 * bx - (bx * (bx - 1)) / 2));
    const bool diag = (bx == by);

    const int tid  = threadIdx.x;
    const int wave = tid >> 6, lane = tid & 63;
    const int quad = lane >> 4, l15 = lane & 15;
    const int rowBase = bx * TILE;
    const int colBase = by * TILE;
    const int waveRow = (wave >> 1) * 64;
    const int waveCol = (wave & 1) * 64;

    f32x4 acc[4][4];
    const f32x4 zero = {0.f, 0.f, 0.f, 0.f};
#pragma unroll
    for (int m = 0; m < 4; m++)
#pragma unroll
        for (int n = 0; n < 4; n++) acc[m][n] = zero;

    const int r16 = lane >> 2;
    const int b4  = lane & 3;
    const int sw  = (r16 >> 1) & 3;   // stage-side swizzle
    const int sr  = (l15 >> 1) & 3;   // read-side swizzle

#define SIM_STAGE(q, k0s)                                                                        \
    {                                                                                            \
        __bf16* aq = (__bf16*)(smem + (q) * 32768);                                              \
        __bf16* bq = (__bf16*)(smem + (q) * 32768 + 16384);                                      \
        _Pragma("unroll")                                                                        \
        for (int c = 0; c < 2; c++) {                                                            \
            _Pragma("unroll")                                                                    \
            for (int j = 0; j < 2; j++) {                                                        \
                int rg = wave * 2 + j;                                                           \
                const __bf16* asrc = X + (size_t)(rowBase + rg * 16 + r16) * DIM + (k0s)         \
                                       + c * 32 + (b4 ^ sw) * 8;                                 \
                const __bf16* bsrc = X + (size_t)(colBase + rg * 16 + r16) * DIM + (k0s)         \
                                       + c * 32 + (b4 ^ sw) * 8;                                 \
                gld_lds16(asrc, aq + (c * TILE + rg * 16) * 32);                                 \
                gld_lds16(bsrc, bq + (c * TILE + rg * 16) * 32);                                 \
            }                                                                                    \
        }                                                                                        \
    }

    // prologue: stage k-chunk 0 into buffer 0
    SIM_STAGE(0, 0)
    __syncthreads();

    for (int k0 = 0; k0 < DIM; k0 += 64) {
        const int q = (k0 >> 6) & 1;
        if (k0 + 64 < DIM) SIM_STAGE(q ^ 1, k0 + 64)
        __bf16* aq = (__bf16*)(smem + q * 32768);
        __bf16* bq = (__bf16*)(smem + q * 32768 + 16384);
#pragma unroll
        for (int ks = 0; ks < 2; ks++) {
            bf16x8v af[4], bfv[4];
#pragma unroll
            for (int m = 0; m < 4; m++)
                af[m] = *(const bf16x8v*)(aq + (ks * TILE + waveRow + m * 16 + l15) * 32 + (quad ^ sr) * 8);
#pragma unroll
            for (int n = 0; n < 4; n++)
                bfv[n] = *(const bf16x8v*)(bq + (ks * TILE + waveCol + n * 16 + l15) * 32 + (quad ^ sr) * 8);
#pragma unroll
            for (int m = 0; m < 4; m++)
#pragma unroll
                for (int n = 0; n < 4; n++)
                    acc[m][n] = __builtin_amdgcn_mfma_f32_16x16x32_bf16(af[m], bfv[n], acc[m][n], 0, 0, 0);
        }
        __syncthreads();   // drains next-chunk gld (issued before compute)
    }

    float es[4][4];
    float ecol[4];
#pragma unroll
    for (int n = 0; n < 4; n++) ecol[n] = 0.f;
#pragma unroll
    for (int m = 0; m < 4; m++) {
#pragma unroll
        for (int r = 0; r < 4; r++) {
            int grow = rowBase + waveRow + m * 16 + quad * 4 + r;
            float e_acc = 0.f;
#pragma unroll
            for (int n = 0; n < 4; n++) {
                int gcol = colBase + waveCol + n * 16 + l15;
                float s = acc[m][n][r];
                if (gcol - grow == HALF) { posv[grow] = s; posv[gcol] = s; }
                float e = (gcol == grow) ? 0.f : __expf(s * INV_T);
                e_acc += e;
                ecol[n] += e;
            }
            es[m][r] = e_acc;
        }
    }

    __syncthreads();   // staging LDS dead; reuse buffer 0 as reduce scratch
    const int wc = wave & 1;
    const int wr = wave >> 1;
#pragma unroll
    for (int m = 0; m < 4; m++)
#pragma unroll
        for (int r = 0; r < 4; r++) {
            int lrow = waveRow + m * 16 + quad * 4 + r;
            rs[(lrow * 2 + wc) * 16 + l15] = es[m][r];
        }
    if (!diag) {
#pragma unroll
        for (int n = 0; n < 4; n++) {
            int lcol = waveCol + n * 16 + l15;
            cs[(lcol * 2 + wr) * 4 + quad] = ecol[n];
        }
    }
    __syncthreads();

    if (tid < TILE) {
        float rsum = 0.f;
#pragma unroll
        for (int i = 0; i < 32; i++) rsum += rs[tid * 32 + i];
        atomicAdd(&total[rowBase + tid], rsum);
        if (!diag) {
            float csum = 0.f;
#pragma unroll
            for (int i = 0; i < 8; i++) csum += cs[tid * 8 + i];
            atomicAdd(&total[colBase + tid], csum);
        }
    }
}

// ---------- K3: loss ----------
__global__ __launch_bounds__(256) void loss_kernel(
    const float* __restrict__ total, const float* __restrict__ posv,
    float* __restrict__ out)
{
    __shared__ float red[4];
    const int tid = threadIdx.x;
    const int i = blockIdx.x * 256 + tid;
    float s = posv[i] * INV_T - __logf(total[i]);
#pragma unroll
    for (int off = 1; off < 64; off <<= 1) s += __shfl_xor(s, off, 64);
    if ((tid & 63) == 0) red[tid >> 6] = s;
    __syncthreads();
    if (tid == 0) {
        float v = red[0] + red[1] + red[2] + red[3];
        atomicAdd(out, -v / (float)NROWS);
    }
}

extern "C" void kernel_launch(void* const* d_in, const int* in_sizes, int n_in,
                              void* d_out, int out_size, void* d_ws, size_t ws_size,
                              hipStream_t stream) {
    const float* emb  = (const float*)d_in[0];
    const float* W    = (const float*)d_in[1];
    const float* bias = (const float*)d_in[2];
    float* out = (float*)d_out;

    char* ws = (char*)d_ws;
    float*  out8  = (float*)ws;                           // 8 MB
    __bf16* outb  = (__bf16*)(ws + (8u << 20));           // 4 MB
    __bf16* Wt    = (__bf16*)(ws + (12u << 20));          // 1 MB
    float*  total = (float*)(ws + (13u << 20));           // 32 KB
    float*  posv  = (float*)(ws + (13u << 20) + (32u << 10));

    hipMemsetAsync(total, 0, NROWS * sizeof(float), stream);
    hipMemsetAsync(out, 0, sizeof(float), stream);

    wt_kernel<<<dim3(DIM / 64, EMB / 64), 256, 0, stream>>>(W, Wt);
    head_gemm<<<dim3(DIM / GBN, NROWS / GBM), 256, 0, stream>>>(emb, Wt, bias, out8);
    norm2_kernel<<<dim3(NROWS / 4), 256, 0, stream>>>(out8, outb);
    sim_kernel<<<dim3(NBLK), 256, 0, stream>>>(outb, total, posv);
    loss_kernel<<<dim3(NROWS / 256), 256, 0, stream>>>(total, posv, out);
}

// Round 8
// 165.962 us; speedup vs baseline: 1.0407x; 1.0407x over previous
//
#include <hip/hip_runtime.h>
#include <math.h>

#define NROWS 8192
#define HALF  4096
#define EMB   2048
#define DIM   256
#define INV_T 10.0f

typedef __bf16 bf16x8v __attribute__((ext_vector_type(8)));
typedef __bf16 bf16x4v __attribute__((ext_vector_type(4)));
typedef float  f32x4   __attribute__((ext_vector_type(4)));

__device__ __forceinline__ void gld_lds16(const void* g, void* l) {
    __builtin_amdgcn_global_load_lds((const __attribute__((address_space(1))) void*)g,
                                     (__attribute__((address_space(3))) void*)l,
                                     16, 0, 0);
}

// ---------- K0: W [2048][256] f32 -> Wt [256][2048] bf16, coalesced tile transpose ----------
__global__ __launch_bounds__(256) void wt_kernel(const float* __restrict__ W,
                                                 __bf16* __restrict__ Wt) {
    __shared__ __bf16 t[64][72];
    const int n0 = blockIdx.x * 64;
    const int k0 = blockIdx.y * 64;
    const int tid = threadIdx.x;
    const int c = tid & 63;
    const int rr = tid >> 6;
#pragma unroll
    for (int it = 0; it < 16; it++) {
        int k = it * 4 + rr;
        t[k][c] = (__bf16)W[(size_t)(k0 + k) * DIM + n0 + c];
    }
    __syncthreads();
#pragma unroll
    for (int it = 0; it < 16; it++) {
        int n = it * 4 + rr;
        Wt[(size_t)(n0 + n) * EMB + k0 + c] = t[c][n];
    }
}

// ---------- K1a: head GEMM. v8: gld_lds RING + COUNTED VMCNT (T3+T4, m201 pattern).
// All previous variants failed the same way: hipcc sinks reg-prefetches (VGPR 40-56)
// and __syncthreads drains vmcnt(0) -> full latency exposed per iter. Fix: stage
// ONLY via global_load_lds (data never in VGPRs -> nothing to sink), 3-deep LDS
// ring, inline-asm s_waitcnt vmcnt(4) (slot t done, stage t+1 still in flight),
// raw s_barrier, sched_barrier(0) fences. Never drains to 0 in the loop.
// Slot: A f32 [32][64] 8KB + B bf16 [64][64] 8KB; 48KB total -> 3 blocks/CU.
// XOR swizzle granule g^(row&7) applied on SOURCE (per-lane global addr) and on
// LDS reads; dest stays linear (rule #21).
#define GBM  32
#define GBN  64
#define GBK  64
#define FNIT (EMB / GBK)   // 32

__global__ __launch_bounds__(256, 3) void head_gemm(
    const float* __restrict__ A,      // [8192][2048] f32
    const __bf16* __restrict__ Wt,    // [256][2048] bf16
    const float* __restrict__ bias,   // [256] f32
    float* __restrict__ out8)         // [8192][256] f32 head+bias
{
    __shared__ __align__(16) char smem[3 * 16384];   // slot s: A at s*16384, B at +8192

    const int tid  = threadIdx.x;
    const int wave = tid >> 6, lane = tid & 63;
    const int quad = lane >> 4, l15 = lane & 15;
    const int rowBase = blockIdx.x * GBM;   // x = row (256 blocks) -> row-fastest
    const int colBase = blockIdx.y * GBN;   // y = col (4)
    const int wr = wave >> 1;   // 0..1: 16-row half
    const int wc = wave & 1;    // 0..1: 32-col half

    // ---- staging descriptors (per-lane source, wave-uniform linear dest) ----
    // A: wave w stages rows w*8..w*8+7 as two 1KB glds (4 rows each).
    //    lane l -> row base+(l>>4), stored granule q=l&15, source granule q^(r&7).
    const int rA0 = wave * 8 + (lane >> 4);
    const int rA1 = rA0 + 4;
    const int qa  = lane & 15;
    const float* aSrc0 = A + (size_t)(rowBase + rA0) * EMB + (qa ^ (rA0 & 7)) * 4;
    const float* aSrc1 = A + (size_t)(rowBase + rA1) * EMB + (qa ^ (rA1 & 7)) * 4;
    const int aOff0 = (wave * 8) * 256;
    const int aOff1 = (wave * 8 + 4) * 256;
    // B: wave w stages cols w*16..w*16+15 as two 1KB glds (8 cols each).
    //    lane l -> col base+(l>>3), stored granule q=l&7, source granule q^(c&7).
    const int cB0 = wave * 16 + (lane >> 3);
    const int cB1 = cB0 + 8;
    const int qb8 = lane & 7;
    const __bf16* bSrc0 = Wt + (size_t)(colBase + cB0) * EMB + (qb8 ^ (cB0 & 7)) * 8;
    const __bf16* bSrc1 = Wt + (size_t)(colBase + cB1) * EMB + (qb8 ^ (cB1 & 7)) * 8;
    const int bOff0 = (wave * 16) * 128;
    const int bOff1 = (wave * 16 + 8) * 128;

    f32x4 acc[2];
    const f32x4 zero = {0.f, 0.f, 0.f, 0.f};
    acc[0] = zero; acc[1] = zero;

#define STAGE(s, kk) {                                              \
        char* base_ = smem + (s) * 16384;                           \
        gld_lds16(aSrc0 + (kk), base_ + aOff0);                     \
        gld_lds16(aSrc1 + (kk), base_ + aOff1);                     \
        gld_lds16(bSrc0 + (kk), base_ + 8192 + bOff0);              \
        gld_lds16(bSrc1 + (kk), base_ + 8192 + bOff1);              \
    }

#define COMPUTE(s) {                                                                 \
        const char* aS_ = smem + (s) * 16384;                                        \
        const char* bS_ = smem + (s) * 16384 + 8192;                                 \
        _Pragma("unroll")                                                            \
        for (int ks = 0; ks < 2; ks++) {                                             \
            const int x_  = ks * 8 + quad * 2;                                       \
            const int q0_ = x_ ^ (l15 & 7);                                          \
            const int ar_ = wr * 16 + l15;                                           \
            f32x4 v0_ = *(const f32x4*)(aS_ + ar_ * 256 + q0_ * 16);                 \
            f32x4 v1_ = *(const f32x4*)(aS_ + ar_ * 256 + (q0_ ^ 1) * 16);           \
            bf16x8v af_;                                                             \
            _Pragma("unroll")                                                        \
            for (int i = 0; i < 4; i++) { af_[i] = (__bf16)v0_[i];                   \
                                          af_[4 + i] = (__bf16)v1_[i]; }             \
            _Pragma("unroll")                                                        \
            for (int n = 0; n < 2; n++) {                                            \
                const int col_ = wc * 32 + n * 16 + l15;                             \
                const int qb_  = (ks * 4 + quad) ^ (col_ & 7);                       \
                bf16x8v bf_ = *(const bf16x8v*)(bS_ + col_ * 128 + qb_ * 16);        \
                acc[n] = __builtin_amdgcn_mfma_f32_16x16x32_bf16(af_, bf_, acc[n],   \
                                                                 0, 0, 0);           \
            }                                                                        \
        }                                                                            \
    }

#define PHASE_S(t, s) {                                             \
        __builtin_amdgcn_sched_barrier(0);                          \
        asm volatile("s_waitcnt vmcnt(4)" ::: "memory");            \
        __builtin_amdgcn_sched_barrier(0);                          \
        __builtin_amdgcn_s_barrier();                               \
        __builtin_amdgcn_sched_barrier(0);                          \
        STAGE(((s) + 2) % 3, ((t) + 2) * GBK);                      \
        COMPUTE(s);                                                 \
    }

    // ---- prologue: stage tiles 0,1 (8 glds in flight) ----
    STAGE(0, 0);
    STAGE(1, GBK);

    // ---- main loop: t = 0..29 (all stage t+2), slots cycle 0,1,2 ----
    for (int i = 0; i < 30; i += 3) {
        PHASE_S(i + 0, 0);
        PHASE_S(i + 1, 1);
        PHASE_S(i + 2, 2);
    }
    // t = 30: no stage; stage(31) still in flight -> vmcnt(4)
    __builtin_amdgcn_sched_barrier(0);
    asm volatile("s_waitcnt vmcnt(4)" ::: "memory");
    __builtin_amdgcn_sched_barrier(0);
    __builtin_amdgcn_s_barrier();
    __builtin_amdgcn_sched_barrier(0);
    COMPUTE(0);
    // t = 31: nothing behind it -> vmcnt(0)
    __builtin_amdgcn_sched_barrier(0);
    asm volatile("s_waitcnt vmcnt(0)" ::: "memory");
    __builtin_amdgcn_sched_barrier(0);
    __builtin_amdgcn_s_barrier();
    __builtin_amdgcn_sched_barrier(0);
    COMPUTE(1);

    // ---- epilogue: + bias, f32 store (bias loaded here so loop vmcnt count is exact) ----
#pragma unroll
    for (int n = 0; n < 2; n++) {
        const float bvn = bias[colBase + wc * 32 + n * 16 + l15];
#pragma unroll
        for (int r = 0; r < 4; r++) {
            const int grow = rowBase + wr * 16 + quad * 4 + r;
            const int gcol = colBase + wc * 32 + n * 16 + l15;
            out8[(size_t)grow * DIM + gcol] = acc[n][r] + bvn;
        }
    }
#undef PHASE_S
#undef COMPUTE
#undef STAGE
}

// ---------- K1b: L2-normalize rows of out8, emit bf16 X ----------
__global__ __launch_bounds__(256) void norm2_kernel(
    const float* __restrict__ out8,
    __bf16* __restrict__ outb)
{
    const int tid  = threadIdx.x;
    const int wave = tid >> 6, lane = tid & 63;
    const int row  = blockIdx.x * 4 + wave;

    float4 v = *(const float4*)(out8 + (size_t)row * DIM + lane * 4);
    float ss = v.x * v.x + v.y * v.y + v.z * v.z + v.w * v.w;
#pragma unroll
    for (int off = 1; off < 64; off <<= 1) ss += __shfl_xor(ss, off, 64);
    float inv = 1.f / fmaxf(sqrtf(ss), 1e-12f);

    bf16x4v o;
    o[0] = (__bf16)(v.x * inv); o[1] = (__bf16)(v.y * inv);
    o[2] = (__bf16)(v.z * inv); o[3] = (__bf16)(v.w * inv);
    *(bf16x4v*)(outb + (size_t)row * DIM + lane * 4) = o;
}

// ---------- K2: sim = X@X^T. (R6 version: 32 KB LDS -> 3 blocks/CU,
//              XOR-swizzled staging, shuffle-free unique-writer LDS epilogue, upper-tri grid) ----------
#define TILE 128
#define NTILE (NROWS / TILE)              // 64
#define NBLK  (NTILE * (NTILE + 1) / 2)   // 2080

__global__ __launch_bounds__(256, 3) void sim_kernel(
    const __bf16* __restrict__ X,
    float* __restrict__ total,
    float* __restrict__ posv)
{
    __shared__ __align__(16) char smem[32768];
    __bf16* a_base = (__bf16*)smem;            // [2][128][32]
    __bf16* b_base = (__bf16*)(smem + 16384);  // [2][128][32]
    float*  rs     = (float*)smem;             // [128][2][16] = 16 KB
    float*  cs     = (float*)(smem + 16384);   // [128][2][4]  = 4 KB

    const int t = blockIdx.x;
    int bx = (int)((129.0 - sqrt(16641.0 - 8.0 * (double)t)) * 0.5);
    while (64 * (bx + 1) - ((bx + 1) * bx) / 2 <= t) bx++;
    while (64 * bx - (bx * (bx - 1)) / 2 > t) bx--;
    const int by = bx + (t - (64 * bx - (bx * (bx - 1)) / 2));
    const bool diag = (bx == by);

    const int tid  = threadIdx.x;
    const int wave = tid >> 6, lane = tid & 63;
    const int quad = lane >> 4, l15 = lane & 15;
    const int rowBase = bx * TILE;
    const int colBase = by * TILE;
    const int waveRow = (wave >> 1) * 64;
    const int waveCol = (wave & 1) * 64;

    f32x4 acc[4][4];
    const f32x4 zero = {0.f, 0.f, 0.f, 0.f};
#pragma unroll
    for (int m = 0; m < 4; m++)
#pragma unroll
        for (int n = 0; n < 4; n++) acc[m][n] = zero;

    const int r16 = lane >> 2;
    const int b4  = lane & 3;
    const int sw  = (r16 >> 1) & 3;   // stage-side swizzle
    const int sr  = (l15 >> 1) & 3;   // read-side swizzle

    for (int k0 = 0; k0 < DIM; k0 += 64) {
        __syncthreads();
#pragma unroll
        for (int c = 0; c < 2; c++) {
#pragma unroll
            for (int j = 0; j < 2; j++) {
                int rg = wave * 2 + j;   // row-group 0..7
                const __bf16* asrc = X + (size_t)(rowBase + rg * 16 + r16) * DIM + k0 + c * 32 + (b4 ^ sw) * 8;
                const __bf16* bsrc = X + (size_t)(colBase + rg * 16 + r16) * DIM + k0 + c * 32 + (b4 ^ sw) * 8;
                gld_lds16(asrc, a_base + (c * TILE + rg * 16) * 32);
                gld_lds16(bsrc, b_base + (c * TILE + rg * 16) * 32);
            }
        }
        __syncthreads();
#pragma unroll
        for (int ks = 0; ks < 2; ks++) {
            bf16x8v af[4], bfv[4];
#pragma unroll
            for (int m = 0; m < 4; m++)
                af[m] = *(const bf16x8v*)(a_base + (ks * TILE + waveRow + m * 16 + l15) * 32 + (quad ^ sr) * 8);
#pragma unroll
            for (int n = 0; n < 4; n++)
                bfv[n] = *(const bf16x8v*)(b_base + (ks * TILE + waveCol + n * 16 + l15) * 32 + (quad ^ sr) * 8);
#pragma unroll
            for (int m = 0; m < 4; m++)
#pragma unroll
                for (int n = 0; n < 4; n++)
                    acc[m][n] = __builtin_amdgcn_mfma_f32_16x16x32_bf16(af[m], bfv[n], acc[m][n], 0, 0, 0);
        }
    }

    float es[4][4];
    float ecol[4];
#pragma unroll
    for (int n = 0; n < 4; n++) ecol[n] = 0.f;
#pragma unroll
    for (int m = 0; m < 4; m++) {
#pragma unroll
        for (int r = 0; r < 4; r++) {
            int grow = rowBase + waveRow + m * 16 + quad * 4 + r;
            float e_acc = 0.f;
#pragma unroll
            for (int n = 0; n < 4; n++) {
                int gcol = colBase + waveCol + n * 16 + l15;
                float s = acc[m][n][r];
                if (gcol - grow == HALF) { posv[grow] = s; posv[gcol] = s; }
                float e = (gcol == grow) ? 0.f : __expf(s * INV_T);
                e_acc += e;
                ecol[n] += e;
            }
            es[m][r] = e_acc;
        }
    }

    __syncthreads();
    const int wc = wave & 1;
    const int wr = wave >> 1;
#pragma unroll
    for (int m = 0; m < 4; m++)
#pragma unroll
        for (int r = 0; r < 4; r++) {
            int lrow = waveRow + m * 16 + quad * 4 + r;
            rs[(lrow * 2 + wc) * 16 + l15] = es[m][r];
        }
    if (!diag) {
#pragma unroll
        for (int n = 0; n < 4; n++) {
            int lcol = waveCol + n * 16 + l15;
            cs[(lcol * 2 + wr) * 4 + quad] = ecol[n];
        }
    }
    __syncthreads();

    if (tid < TILE) {
        float rsum = 0.f;
#pragma unroll
        for (int i = 0; i < 32; i++) rsum += rs[tid * 32 + i];
        atomicAdd(&total[rowBase + tid], rsum);
        if (!diag) {
            float csum = 0.f;
#pragma unroll
            for (int i = 0; i < 8; i++) csum += cs[tid * 8 + i];
            atomicAdd(&total[colBase + tid], csum);
        }
    }
}

// ---------- K3: loss ----------
__global__ __launch_bounds__(256) void loss_kernel(
    const float* __restrict__ total, const float* __restrict__ posv,
    float* __restrict__ out)
{
    __shared__ float red[4];
    const int tid = threadIdx.x;
    const int i = blockIdx.x * 256 + tid;
    float s = posv[i] * INV_T - __logf(total[i]);
#pragma unroll
    for (int off = 1; off < 64; off <<= 1) s += __shfl_xor(s, off, 64);
    if ((tid & 63) == 0) red[tid >> 6] = s;
    __syncthreads();
    if (tid == 0) {
        float v = red[0] + red[1] + red[2] + red[3];
        atomicAdd(out, -v / (float)NROWS);
    }
}

extern "C" void kernel_launch(void* const* d_in, const int* in_sizes, int n_in,
                              void* d_out, int out_size, void* d_ws, size_t ws_size,
                              hipStream_t stream) {
    const float* emb  = (const float*)d_in[0];
    const float* W    = (const float*)d_in[1];
    const float* bias = (const float*)d_in[2];
    float* out = (float*)d_out;

    char* ws = (char*)d_ws;
    float*  out8  = (float*)ws;                           // 8 MB
    __bf16* outb  = (__bf16*)(ws + (8u << 20));           // 4 MB
    __bf16* Wt    = (__bf16*)(ws + (12u << 20));          // 1 MB
    float*  total = (float*)(ws + (13u << 20));           // 32 KB
    float*  posv  = (float*)(ws + (13u << 20) + (32u << 10));

    hipMemsetAsync(total, 0, NROWS * sizeof(float), stream);
    hipMemsetAsync(out, 0, sizeof(float), stream);

    wt_kernel<<<dim3(DIM / 64, EMB / 64), 256, 0, stream>>>(W, Wt);
    head_gemm<<<dim3(NROWS / GBM, DIM / GBN), 256, 0, stream>>>(emb, Wt, bias, out8);
    norm2_kernel<<<dim3(NROWS / 4), 256, 0, stream>>>(out8, outb);
    sim_kernel<<<dim3(NBLK), 256, 0, stream>>>(outb, total, posv);
    loss_kernel<<<dim3(NROWS / 256), 256, 0, stream>>>(total, posv, out);
}

// Round 9
// 161.611 us; speedup vs baseline: 1.0687x; 1.0269x over previous
//
#include <hip/hip_runtime.h>
#include <math.h>

#define NROWS 8192
#define HALF  4096
#define EMB   2048
#define DIM   256
#define INV_T 10.0f

typedef __bf16 bf16x8v __attribute__((ext_vector_type(8)));
typedef __bf16 bf16x4v __attribute__((ext_vector_type(4)));
typedef float  f32x4   __attribute__((ext_vector_type(4)));

__device__ __forceinline__ void gld_lds16(const void* g, void* l) {
    __builtin_amdgcn_global_load_lds((const __attribute__((address_space(1))) void*)g,
                                     (__attribute__((address_space(3))) void*)l,
                                     16, 0, 0);
}

// ---------- K0: W [2048][256] f32 -> Wt [256][2048] bf16, coalesced tile transpose ----------
__global__ __launch_bounds__(256) void wt_kernel(const float* __restrict__ W,
                                                 __bf16* __restrict__ Wt) {
    __shared__ __bf16 t[64][72];
    const int n0 = blockIdx.x * 64;
    const int k0 = blockIdx.y * 64;
    const int tid = threadIdx.x;
    const int c = tid & 63;
    const int rr = tid >> 6;
#pragma unroll
    for (int it = 0; it < 16; it++) {
        int k = it * 4 + rr;
        t[k][c] = (__bf16)W[(size_t)(k0 + k) * DIM + n0 + c];
    }
    __syncthreads();
#pragma unroll
    for (int it = 0; it < 16; it++) {
        int n = it * 4 + rr;
        Wt[(size_t)(n0 + n) * EMB + k0 + c] = t[c][n];
    }
}

// ---------- K1a: head GEMM. v9 = v6 body (best measured) + L2-LOCALITY DISPATCH SWIZZLE.
// Evidence: v7 (same-stripe blocks simultaneous, cross-XCD) FETCH=132MB (concurrent
// L3 misses don't merge); v6/v8 (col phases ~100 blocks apart) FETCH=104MB (L3
// partial eviction). Ideal A traffic is 64MB. Decode b -> {super=b>>7,
// col=(b&127)>>5, stripe=super*32+(b&31)}: same-stripe col-blocks are 32 slots
// apart (not simultaneous, still resident) AND land on the SAME XCD
// (b mod 8 invariant across the quartet) -> re-reads hit that XCD's private L2
// (4 stripes x 256KB + Wt 1MB = 2MB < 4MB L2). A leaves HBM exactly once.
#define GBM 32
#define GBN 64
#define GBK 64

__global__ __launch_bounds__(256, 4) void head_gemm(
    const float* __restrict__ A,      // [8192][2048] f32
    const __bf16* __restrict__ Wt,    // [256][2048] bf16
    const float* __restrict__ bias,   // [256] f32
    float* __restrict__ out8)         // [8192][256] f32 head+bias
{
    __shared__ __bf16 a_sh[GBM][GBK];   // 4 KB
    __shared__ __bf16 b_sh[GBN][GBK];   // 8 KB

    const int tid  = threadIdx.x;
    const int wave = tid >> 6, lane = tid & 63;
    const int quad = lane >> 4, l15 = lane & 15;

    // L2-locality swizzle (see header comment)
    const int b      = blockIdx.x;
    const int superg = b >> 7;
    const int inner  = b & 127;
    const int colblk = inner >> 5;               // 0..3
    const int stripe = superg * 32 + (inner & 31);  // 0..255
    const int rowBase = stripe * GBM;
    const int colBase = colblk * GBN;

    const int wr = wave >> 1;   // 0..1: 16-row half
    const int wc = wave & 1;    // 0..1: 32-col half

    // A staging: thread -> row tid>>3 (0..31), granule tid&7 (8 f32 -> 8 bf16)
    const int ar = tid >> 3, ag = tid & 7;
    const float* aPtr = A + (size_t)(rowBase + ar) * EMB + ag * 8;
    __bf16* aDst = &a_sh[ar][(ag ^ (ar & 7)) * 8];

    // B staging: wave stages chunks {wave*2, wave*2+1}; chunk = 8 cols = 1KB.
    // source granule pre-swizzled g ^ (col&7); LDS dest linear (rule #21).
    size_t bSrcOff[2];
    __bf16* bDst[2];
#pragma unroll
    for (int j = 0; j < 2; j++) {
        const int chunk = wave * 2 + j;
        const int c = chunk * 8 + (lane >> 3);
        const int g = lane & 7;
        bSrcOff[j] = (size_t)(colBase + c) * EMB + (g ^ (c & 7)) * 8;
        bDst[j]    = &b_sh[0][0] + chunk * 512;   // 512 bf16 = 1KB
    }

    f32x4 acc[2];
    const f32x4 zero = {0.f, 0.f, 0.f, 0.f};
    acc[0] = zero; acc[1] = zero;

    float bv[2];
#pragma unroll
    for (int n = 0; n < 2; n++) bv[n] = bias[colBase + wc * 32 + n * 16 + l15];

    for (int kk = 0; kk < EMB; kk += GBK) {
        __syncthreads();
        // stage A (reg roundtrip for f32->bf16)
        f32x4 lo = *(const f32x4*)(aPtr + kk);
        f32x4 hi = *(const f32x4*)(aPtr + kk + 4);
        // stage B (async direct to LDS, source-swizzled)
        gld_lds16(Wt + bSrcOff[0] + kk, bDst[0]);
        gld_lds16(Wt + bSrcOff[1] + kk, bDst[1]);
        bf16x8v av;
#pragma unroll
        for (int i = 0; i < 4; i++) { av[i] = (__bf16)lo[i]; av[4 + i] = (__bf16)hi[i]; }
        *(bf16x8v*)aDst = av;
        __syncthreads();
        // compute
#pragma unroll
        for (int ks = 0; ks < 2; ks++) {
            const int arow = wr * 16 + l15;
            bf16x8v af = *(const bf16x8v*)&a_sh[arow][(((ks * 4 + quad) ^ (arow & 7)) * 8)];
#pragma unroll
            for (int n = 0; n < 2; n++) {
                const int col = wc * 32 + n * 16 + l15;
                bf16x8v bf = *(const bf16x8v*)&b_sh[col][(((ks * 4 + quad) ^ (col & 7)) * 8)];
                acc[n] = __builtin_amdgcn_mfma_f32_16x16x32_bf16(af, bf, acc[n], 0, 0, 0);
            }
        }
    }

    // epilogue: + bias, f32 store
#pragma unroll
    for (int n = 0; n < 2; n++)
#pragma unroll
        for (int r = 0; r < 4; r++) {
            const int grow = rowBase + wr * 16 + quad * 4 + r;
            const int gcol = colBase + wc * 32 + n * 16 + l15;
            out8[(size_t)grow * DIM + gcol] = acc[n][r] + bv[n];
        }
}

// ---------- K1b: L2-normalize rows of out8, emit bf16 X ----------
__global__ __launch_bounds__(256) void norm2_kernel(
    const float* __restrict__ out8,
    __bf16* __restrict__ outb)
{
    const int tid  = threadIdx.x;
    const int wave = tid >> 6, lane = tid & 63;
    const int row  = blockIdx.x * 4 + wave;

    float4 v = *(const float4*)(out8 + (size_t)row * DIM + lane * 4);
    float ss = v.x * v.x + v.y * v.y + v.z * v.z + v.w * v.w;
#pragma unroll
    for (int off = 1; off < 64; off <<= 1) ss += __shfl_xor(ss, off, 64);
    float inv = 1.f / fmaxf(sqrtf(ss), 1e-12f);

    bf16x4v o;
    o[0] = (__bf16)(v.x * inv); o[1] = (__bf16)(v.y * inv);
    o[2] = (__bf16)(v.z * inv); o[3] = (__bf16)(v.w * inv);
    *(bf16x4v*)(outb + (size_t)row * DIM + lane * 4) = o;
}

// ---------- K2: sim = X@X^T. (R6 version: 32 KB LDS -> 3 blocks/CU,
//              XOR-swizzled staging, shuffle-free unique-writer LDS epilogue, upper-tri grid) ----------
#define TILE 128
#define NTILE (NROWS / TILE)              // 64
#define NBLK  (NTILE * (NTILE + 1) / 2)   // 2080

__global__ __launch_bounds__(256, 3) void sim_kernel(
    const __bf16* __restrict__ X,
    float* __restrict__ total,
    float* __restrict__ posv)
{
    __shared__ __align__(16) char smem[32768];
    __bf16* a_base = (__bf16*)smem;            // [2][128][32]
    __bf16* b_base = (__bf16*)(smem + 16384);  // [2][128][32]
    float*  rs     = (float*)smem;             // [128][2][16] = 16 KB
    float*  cs     = (float*)(smem + 16384);   // [128][2][4]  = 4 KB

    const int t = blockIdx.x;
    int bx = (int)((129.0 - sqrt(16641.0 - 8.0 * (double)t)) * 0.5);
    while (64 * (bx + 1) - ((bx + 1) * bx) / 2 <= t) bx++;
    while (64 * bx - (bx * (bx - 1)) / 2 > t) bx--;
    const int by = bx + (t - (64 * bx - (bx * (bx - 1)) / 2));
    const bool diag = (bx == by);

    const int tid  = threadIdx.x;
    const int wave = tid >> 6, lane = tid & 63;
    const int quad = lane >> 4, l15 = lane & 15;
    const int rowBase = bx * TILE;
    const int colBase = by * TILE;
    const int waveRow = (wave >> 1) * 64;
    const int waveCol = (wave & 1) * 64;

    f32x4 acc[4][4];
    const f32x4 zero = {0.f, 0.f, 0.f, 0.f};
#pragma unroll
    for (int m = 0; m < 4; m++)
#pragma unroll
        for (int n = 0; n < 4; n++) acc[m][n] = zero;

    const int r16 = lane >> 2;
    const int b4  = lane & 3;
    const int sw  = (r16 >> 1) & 3;   // stage-side swizzle
    const int sr  = (l15 >> 1) & 3;   // read-side swizzle

    for (int k0 = 0; k0 < DIM; k0 += 64) {
        __syncthreads();
#pragma unroll
        for (int c = 0; c < 2; c++) {
#pragma unroll
            for (int j = 0; j < 2; j++) {
                int rg = wave * 2 + j;   // row-group 0..7
                const __bf16* asrc = X + (size_t)(rowBase + rg * 16 + r16) * DIM + k0 + c * 32 + (b4 ^ sw) * 8;
                const __bf16* bsrc = X + (size_t)(colBase + rg * 16 + r16) * DIM + k0 + c * 32 + (b4 ^ sw) * 8;
                gld_lds16(asrc, a_base + (c * TILE + rg * 16) * 32);
                gld_lds16(bsrc, b_base + (c * TILE + rg * 16) * 32);
            }
        }
        __syncthreads();
#pragma unroll
        for (int ks = 0; ks < 2; ks++) {
            bf16x8v af[4], bfv[4];
#pragma unroll
            for (int m = 0; m < 4; m++)
                af[m] = *(const bf16x8v*)(a_base + (ks * TILE + waveRow + m * 16 + l15) * 32 + (quad ^ sr) * 8);
#pragma unroll
            for (int n = 0; n < 4; n++)
                bfv[n] = *(const bf16x8v*)(b_base + (ks * TILE + waveCol + n * 16 + l15) * 32 + (quad ^ sr) * 8);
#pragma unroll
            for (int m = 0; m < 4; m++)
#pragma unroll
                for (int n = 0; n < 4; n++)
                    acc[m][n] = __builtin_amdgcn_mfma_f32_16x16x32_bf16(af[m], bfv[n], acc[m][n], 0, 0, 0);
        }
    }

    float es[4][4];
    float ecol[4];
#pragma unroll
    for (int n = 0; n < 4; n++) ecol[n] = 0.f;
#pragma unroll
    for (int m = 0; m < 4; m++) {
#pragma unroll
        for (int r = 0; r < 4; r++) {
            int grow = rowBase + waveRow + m * 16 + quad * 4 + r;
            float e_acc = 0.f;
#pragma unroll
            for (int n = 0; n < 4; n++) {
                int gcol = colBase + waveCol + n * 16 + l15;
                float s = acc[m][n][r];
                if (gcol - grow == HALF) { posv[grow] = s; posv[gcol] = s; }
                float e = (gcol == grow) ? 0.f : __expf(s * INV_T);
                e_acc += e;
                ecol[n] += e;
            }
            es[m][r] = e_acc;
        }
    }

    __syncthreads();
    const int wc = wave & 1;
    const int wr = wave >> 1;
#pragma unroll
    for (int m = 0; m < 4; m++)
#pragma unroll
        for (int r = 0; r < 4; r++) {
            int lrow = waveRow + m * 16 + quad * 4 + r;
            rs[(lrow * 2 + wc) * 16 + l15] = es[m][r];
        }
    if (!diag) {
#pragma unroll
        for (int n = 0; n < 4; n++) {
            int lcol = waveCol + n * 16 + l15;
            cs[(lcol * 2 + wr) * 4 + quad] = ecol[n];
        }
    }
    __syncthreads();

    if (tid < TILE) {
        float rsum = 0.f;
#pragma unroll
        for (int i = 0; i < 32; i++) rsum += rs[tid * 32 + i];
        atomicAdd(&total[rowBase + tid], rsum);
        if (!diag) {
            float csum = 0.f;
#pragma unroll
            for (int i = 0; i < 8; i++) csum += cs[tid * 8 + i];
            atomicAdd(&total[colBase + tid], csum);
        }
    }
}

// ---------- K3: loss ----------
__global__ __launch_bounds__(256) void loss_kernel(
    const float* __restrict__ total, const float* __restrict__ posv,
    float* __restrict__ out)
{
    __shared__ float red[4];
    const int tid = threadIdx.x;
    const int i = blockIdx.x * 256 + tid;
    float s = posv[i] * INV_T - __logf(total[i]);
#pragma unroll
    for (int off = 1; off < 64; off <<= 1) s += __shfl_xor(s, off, 64);
    if ((tid & 63) == 0) red[tid >> 6] = s;
    __syncthreads();
    if (tid == 0) {
        float v = red[0] + red[1] + red[2] + red[3];
        atomicAdd(out, -v / (float)NROWS);
    }
}

extern "C" void kernel_launch(void* const* d_in, const int* in_sizes, int n_in,
                              void* d_out, int out_size, void* d_ws, size_t ws_size,
                              hipStream_t stream) {
    const float* emb  = (const float*)d_in[0];
    const float* W    = (const float*)d_in[1];
    const float* bias = (const float*)d_in[2];
    float* out = (float*)d_out;

    char* ws = (char*)d_ws;
    float*  out8  = (float*)ws;                           // 8 MB
    __bf16* outb  = (__bf16*)(ws + (8u << 20));           // 4 MB
    __bf16* Wt    = (__bf16*)(ws + (12u << 20));          // 1 MB
    float*  total = (float*)(ws + (13u << 20));           // 32 KB
    float*  posv  = (float*)(ws + (13u << 20) + (32u << 10));

    hipMemsetAsync(total, 0, NROWS * sizeof(float), stream);
    hipMemsetAsync(out, 0, sizeof(float), stream);

    wt_kernel<<<dim3(DIM / 64, EMB / 64), 256, 0, stream>>>(W, Wt);
    head_gemm<<<dim3((NROWS / GBM) * (DIM / GBN)), 256, 0, stream>>>(emb, Wt, bias, out8);
    norm2_kernel<<<dim3(NROWS / 4), 256, 0, stream>>>(out8, outb);
    sim_kernel<<<dim3(NBLK), 256, 0, stream>>>(outb, total, posv);
    loss_kernel<<<dim3(NROWS / 256), 256, 0, stream>>>(total, posv, out);
}